// Round 2
// 539.507 us; speedup vs baseline: 1.0626x; 1.0626x over previous
//
#include <hip/hip_runtime.h>
#include <cstddef>
#include <cstdint>

#define HEADS 8
#define DH 64
#define C 512
#define TC 1536
#define BT 32
#define NTOK 2304
#define TT 16
#define EPS 1e-6f

typedef __attribute__((ext_vector_type(8))) short bf16x8;
typedef __attribute__((ext_vector_type(4))) float f32x4;
typedef __attribute__((address_space(3))) void as3_void;
typedef __attribute__((address_space(1))) const void as1_cvoid;

__device__ __forceinline__ float fmap(float x) {
    return x > 0.f ? x + 1.f : __expf(x);
}
__device__ __forceinline__ unsigned short f2bf(float f) {
    unsigned int u = __float_as_uint(f);
    return (unsigned short)((u + 0x7fffu + ((u >> 16) & 1u)) >> 16);
}
__device__ __forceinline__ unsigned int pack2bf(float a, float b) {
    return (unsigned int)f2bf(a) | ((unsigned int)f2bf(b) << 16);
}
__device__ __forceinline__ float bf2f(unsigned short h) {
    return __uint_as_float(((unsigned int)h) << 16);
}
// async global->LDS DMA, 16B/lane. LDS dest = wave-uniform base + lane*16.
__device__ __forceinline__ void gload16(const void* g, void* l) {
    __builtin_amdgcn_global_load_lds((as1_cvoid*)(uintptr_t)g,
                                     (as3_void*)(uintptr_t)l, 16, 0, 0);
}

// ---------------------------------------------------------------------------
// K0: Wt[col][c] (bf16) = W[c][col]. grid (48,16).
// ---------------------------------------------------------------------------
__global__ __launch_bounds__(256) void k_prep_w(
    const float* __restrict__ W, unsigned short* __restrict__ Wt) {
    __shared__ float tile[32][33];
    int col0 = blockIdx.x * 32, c0 = blockIdx.y * 32;
    int tx = threadIdx.x & 31, ty = threadIdx.x >> 5;
#pragma unroll
    for (int j = 0; j < 4; ++j) {
        int c = ty + j * 8;
        tile[c][tx] = W[(size_t)(c0 + c) * TC + col0 + tx];
    }
    __syncthreads();
#pragma unroll
    for (int j = 0; j < 4; ++j) {
        int col = ty + j * 8;
        Wt[(size_t)(col0 + col) * C + c0 + tx] = f2bf(tile[tx][col]);
    }
}

// ---------------------------------------------------------------------------
// K1: x_time channel sums + motion mean sums + stage xb = bf16(x).
// grid (BT, 8), block 256; thread <-> 2 consecutive channels.
// ---------------------------------------------------------------------------
__global__ __launch_bounds__(256) void k_time_reduce(
    const float* __restrict__ x, const float* __restrict__ motion,
    float* __restrict__ xtraw, float* __restrict__ mmraw,
    unsigned short* __restrict__ xb) {
    int bt = blockIdx.x, sp = blockIdx.y, tid = threadIdx.x;
    int n0 = sp * 288, cid = tid * 2;
    const float* xp = x + ((size_t)(bt * NTOK + n0)) * C + cid;
    unsigned short* xbp = xb + ((size_t)(bt * NTOK + n0)) * C + cid;
    float s0 = 0.f, s1 = 0.f;
    for (int n = 0; n < 288; ++n) {
        float2 v = *(const float2*)(xp + (size_t)n * C);
        s0 += v.x;
        s1 += v.y;
        *(unsigned int*)(xbp + (size_t)n * C) = pack2bf(v.x, v.y);
    }
    atomicAdd(&xtraw[bt * C + cid], s0);
    atomicAdd(&xtraw[bt * C + cid + 1], s1);

    const float* mp = motion + (size_t)bt * NTOK + n0;
    float m = mp[tid];
    if (tid < 32) m += mp[256 + tid];
    __shared__ float red[256];
    red[tid] = m;
    __syncthreads();
    for (int s = 128; s > 0; s >>= 1) {
        if (tid < s) red[tid] += red[tid + s];
        __syncthreads();
    }
    if (tid == 0) atomicAdd(&mmraw[bt], red[0]);
}

// ---------------------------------------------------------------------------
// K2a: qkv_time[bt][col] = x_time[bt] @ W.  grid (BT, 6).
// ---------------------------------------------------------------------------
__global__ __launch_bounds__(256) void k_time_qkv(
    const float* __restrict__ xtraw, const float* __restrict__ temb,
    const float* __restrict__ W, float* __restrict__ qkvt) {
    int bt = blockIdx.x, col = blockIdx.y * 256 + threadIdx.x, tid = threadIdx.x;
    __shared__ float xl[C];
    xl[tid]       = xtraw[bt * C + tid]       * (1.f / NTOK) + temb[tid];
    xl[tid + 256] = xtraw[bt * C + tid + 256] * (1.f / NTOK) + temb[tid + 256];
    __syncthreads();
    float a = 0.f;
#pragma unroll 8
    for (int c = 0; c < C; ++c) a += xl[c] * W[(size_t)c * TC + col];
    qkvt[(size_t)bt * TC + col] = a;
}

// ---------------------------------------------------------------------------
// K2b: temporal linear attention -> bias[bt][c] = temb[c] + t_out.
// ---------------------------------------------------------------------------
__global__ __launch_bounds__(256) void k_time_attn(
    const float* __restrict__ qkvt, const float* __restrict__ mmraw,
    const float* __restrict__ temb, float* __restrict__ bias) {
    int b = blockIdx.x, h = blockIdx.y, tid = threadIdx.x;
    int d = tid & 63, g = tid >> 6;
    __shared__ float qs[TT][DH], ks[TT][DH], vs[TT][DH], ksum[DH];
    __shared__ float kvl[DH][DH];
    for (int t = g; t < TT; t += 4) {
        size_t base = (size_t)(b * TT + t) * TC + h * DH + d;
        float mwt = 1.f + tanhf(mmraw[b * TT + t] * (1.f / NTOK));
        qs[t][d] = fmap(qkvt[base]) * mwt;
        ks[t][d] = fmap(qkvt[base + C]);
        vs[t][d] = qkvt[base + 2 * C];
    }
    __syncthreads();
    if (g == 0) {
        float s = 0.f;
        for (int t = 0; t < TT; ++t) s += ks[t][d];
        ksum[d] = s;
    }
    float kva[16];
#pragma unroll
    for (int i = 0; i < 16; ++i) kva[i] = 0.f;
    for (int t = 0; t < TT; ++t) {
        float kd = ks[t][d];
#pragma unroll
        for (int i = 0; i < 16; ++i) kva[i] += kd * vs[t][g * 16 + i];
    }
#pragma unroll
    for (int i = 0; i < 16; ++i) kvl[d][g * 16 + i] = kva[i];
    __syncthreads();
    for (int tt = 0; tt < 4; ++tt) {
        int t = g * 4 + tt;
        float acc = 0.f, zden = 0.f;
        for (int dd = 0; dd < DH; ++dd) {
            float qv = qs[t][dd];
            acc  += qv * kvl[dd][d];
            zden += qv * ksum[dd];
        }
        bias[(size_t)(b * TT + t) * C + h * DH + d] =
            acc / (zden + EPS) + temb[h * DH + d];
    }
}

// ---------------------------------------------------------------------------
// K2c: bvec[bt][col] = bias[bt] @ W.  grid (BT, 6).
// ---------------------------------------------------------------------------
__global__ __launch_bounds__(256) void k_bias_vec(
    const float* __restrict__ bias, const float* __restrict__ W,
    float* __restrict__ bvec) {
    int bt = blockIdx.x, col = blockIdx.y * 256 + threadIdx.x, tid = threadIdx.x;
    __shared__ float bl[C];
    bl[tid]       = bias[bt * C + tid];
    bl[tid + 256] = bias[bt * C + tid + 256];
    __syncthreads();
    float a = 0.f;
#pragma unroll 8
    for (int c = 0; c < C; ++c) a += bl[c] * W[(size_t)c * TC + col];
    bvec[(size_t)bt * TC + col] = a;
}

// ---------------------------------------------------------------------------
// K3: spatial pass A. grid (6, 4 head-pairs, BT), 512 threads (8 waves).
// Per tile (128 tok): GEMM xb@W -> k|v for 2 heads (256 cols), BK=64.
// 2-phase double-buffered staging (T3 minimum recipe, catalog): issue the
// kc+1 STAGE *before* computing kc; the end-of-step __syncthreads() (compiler
// emits vmcnt(0)+barrier) drains AFTER the MFMA phase, so DMA latency hides
// under compute. Plain __syncthreads only — no hand-counted vmcnt, no raw
// barriers. Epilogue unchanged: +bvec, fmap(k), kv += kT@v, ksum; atomics.
// kvT aliases B0 (kc=7 computes from buf1, so B0 is dead in the epilogue).
// ---------------------------------------------------------------------------
__global__ __launch_bounds__(512) void k_spatial_kv(
    const unsigned short* __restrict__ xb, const unsigned short* __restrict__ Wt,
    const float* __restrict__ bvec, float* __restrict__ kvw,
    float* __restrict__ ksw) {
    __shared__ __align__(16) char smem[99328];
    unsigned short* A0 = (unsigned short*)smem;              // 128 x 64 sh
    unsigned short* B0 = (unsigned short*)(smem + 16384);    // 256 x 64 sh
    unsigned short* A1 = (unsigned short*)(smem + 49152);    // 128 x 64 sh
    unsigned short* B1 = (unsigned short*)(smem + 65536);    // 256 x 64 sh
    char* kvT = smem + 16384;       // alias B0 (kc=7 computes from buf1)
    float* bvl = (float*)(smem + 98304);                     // 256

    const int s = blockIdx.x, hp = blockIdx.y, bt = blockIdx.z;
    const int tid = threadIdx.x, lane = tid & 63, w = tid >> 6;
    const int lm = lane & 15, quad = lane >> 4;
    const int mr = w & 1, nc = w >> 1;
    const int li8 = lane >> 3, lp = lane & 7;

    if (tid < 256) {
        int h2 = tid >> 7, j2 = tid & 127;
        int wr = (j2 < 64) ? (C + (hp * 2 + h2) * DH + j2)
                           : (2 * C + (hp * 2 + h2) * DH + (j2 - 64));
        bvl[tid] = bvec[(size_t)bt * TC + wr];
    }
    // per-lane global source bases (constant over t, kc)
    const unsigned short* srcA[2];
#pragma unroll
    for (int l = 0; l < 2; ++l) {
        int row = w * 16 + l * 8 + li8;
        int c = lp ^ (row & 7);
        srcA[l] = xb + ((size_t)(bt * NTOK + row)) * C + c * 8;
    }
    const unsigned short* srcB[4];
#pragma unroll
    for (int l = 0; l < 4; ++l) {
        int r = w * 32 + l * 8 + li8;
        int c = lp ^ (r & 7);
        int h2 = r >> 7, j2 = r & 127;
        int wr = (j2 < 64) ? (C + (hp * 2 + h2) * DH + j2)
                           : (2 * C + (hp * 2 + h2) * DH + (j2 - 64));
        srcB[l] = Wt + (size_t)wr * C + c * 8;
    }

    float ksp0 = 0.f, ksp1 = 0.f;
    f32x4 kvacc[2][2];
#pragma unroll
    for (int a = 0; a < 2; ++a)
#pragma unroll
        for (int b = 0; b < 2; ++b) kvacc[a][b] = (f32x4)0.f;

    // issue one K-step's 6 DMA loads (per lane) into buf (As,Bs)
    auto STAGE = [&](unsigned short* As, unsigned short* Bs, int n0, int kc) {
#pragma unroll
        for (int l = 0; l < 2; ++l)
            gload16(srcA[l] + (size_t)n0 * C + kc * 64, As + (w * 16 + l * 8) * 64);
#pragma unroll
        for (int l = 0; l < 4; ++l)
            gload16(srcB[l] + kc * 64, Bs + (w * 32 + l * 8) * 64);
    };

#pragma unroll 1
    for (int t = 0; t < 3; ++t) {
        const int n0 = (s * 3 + t) * 128;
        f32x4 acc[4][4];
#pragma unroll
        for (int i = 0; i < 4; ++i)
#pragma unroll
            for (int j = 0; j < 4; ++j) acc[i][j] = (f32x4)0.f;

        STAGE(A0, B0, n0, 0);  // prologue: kc=0 -> buf0
        __syncthreads();       // buf0 staged, all waves synced
#pragma unroll
        for (int kc = 0; kc < 8; ++kc) {
            const unsigned short* As = (kc & 1) ? A1 : A0;
            const unsigned short* Bs = (kc & 1) ? B1 : B0;
            if (kc < 7) {
                // prefetch kc+1 into the other buffer; loads stay in flight
                // across the compute phase below.
                STAGE((kc & 1) ? A0 : A1, (kc & 1) ? B0 : B1, n0, kc + 1);
                __builtin_amdgcn_sched_barrier(0);  // pin: issue before compute
            }
#pragma unroll
            for (int ks = 0; ks < 2; ++ks) {
                bf16x8 af[4], bfr[4];
#pragma unroll
                for (int i = 0; i < 4; ++i) {
                    int row = mr * 64 + i * 16 + lm;
                    int p = (ks * 4 + quad) ^ (row & 7);
                    af[i] = *(const bf16x8*)&As[row * 64 + p * 8];
                }
#pragma unroll
                for (int j = 0; j < 4; ++j) {
                    int row = nc * 64 + j * 16 + lm;
                    int p = (ks * 4 + quad) ^ (row & 7);
                    bfr[j] = *(const bf16x8*)&Bs[row * 64 + p * 8];
                }
#pragma unroll
                for (int i = 0; i < 4; ++i)
#pragma unroll
                    for (int j = 0; j < 4; ++j)
                        acc[i][j] = __builtin_amdgcn_mfma_f32_16x16x32_bf16(
                            af[i], bfr[j], acc[i][j], 0, 0, 0);
            }
            // drains vmcnt(0) (prefetch had the whole MFMA phase to land)
            // and gates buffer reuse for the next step.
            __syncthreads();
        }
        // ---- epilogue: per head of the pair (kvT aliases B0; kc=7 used buf1) ----
#pragma unroll 1
        for (int ph = 0; ph < 2; ++ph) {
            __syncthreads();
            if ((nc >> 1) == ph) {  // waves holding this head's 128 cols write kvT
#pragma unroll
                for (int i = 0; i < 4; ++i) {
                    int tokb = mr * 64 + i * 16 + quad * 4;
                    int tc = tokb >> 3;
#pragma unroll
                    for (int j = 0; j < 4; ++j) {
                        int cg = nc * 64 + j * 16 + lm;
                        int cl = cg & 127;
                        float bv = bvl[cg];
                        f32x4 a4 = acc[i][j];
                        float v0 = a4[0] + bv, v1 = a4[1] + bv;
                        float v2 = a4[2] + bv, v3 = a4[3] + bv;
                        if (cl < 64) {
                            v0 = fmap(v0); v1 = fmap(v1);
                            v2 = fmap(v2); v3 = fmap(v3);
                        }
                        int p = (tc & 8) | ((tc & 7) ^ (cl & 7));
                        uint2 pk;
                        pk.x = pack2bf(v0, v1);
                        pk.y = pack2bf(v2, v3);
                        *(uint2*)(kvT + cl * 256 + p * 16 + (tokb & 7) * 2) = pk;
                    }
                }
            }
            __syncthreads();
            if (tid < 128) {  // ksum partials: (d, token-half)
                int d = tid & 63, half = tid >> 6;
                float ssum = 0.f;
#pragma unroll
                for (int tc2 = 0; tc2 < 8; ++tc2) {
                    int tcc = half * 8 + tc2;
                    int p = (tcc & 8) | ((tcc & 7) ^ (d & 7));
                    bf16x8 v8 = *(const bf16x8*)(kvT + d * 256 + p * 16);
#pragma unroll
                    for (int q = 0; q < 8; ++q)
                        ssum += bf2f((unsigned short)v8[q]);
                }
                if (ph == 0) ksp0 += ssum; else ksp1 += ssum;
            }
            // kv += kT @ v (K = 128 tokens); wave -> (dt pair, et)
#pragma unroll
            for (int dt2 = 0; dt2 < 2; ++dt2) {
                int drow = (mr * 2 + dt2) * 16 + lm;
                int erow = 64 + nc * 16 + lm;
#pragma unroll
                for (int ks2 = 0; ks2 < 4; ++ks2) {
                    int tcc = ks2 * 4 + quad;
                    int pA = (tcc & 8) | ((tcc & 7) ^ (drow & 7));
                    int pB = (tcc & 8) | ((tcc & 7) ^ (erow & 7));
                    bf16x8 ak = *(const bf16x8*)(kvT + drow * 256 + pA * 16);
                    bf16x8 bv8 = *(const bf16x8*)(kvT + erow * 256 + pB * 16);
                    kvacc[ph][dt2] = __builtin_amdgcn_mfma_f32_16x16x32_bf16(
                        ak, bv8, kvacc[ph][dt2], 0, 0, 0);
                }
            }
        }
        __syncthreads();  // kvT (=B0) reads done before next tile's prefetch
    }
#pragma unroll
    for (int ph = 0; ph < 2; ++ph) {
        float* kvp = kvw + (size_t)(bt * HEADS + hp * 2 + ph) * DH * DH;
#pragma unroll
        for (int dt2 = 0; dt2 < 2; ++dt2) {
            int d0 = (mr * 2 + dt2) * 16 + quad * 4;
            int e = nc * 16 + lm;
#pragma unroll
            for (int r = 0; r < 4; ++r)
                atomicAdd(&kvp[(d0 + r) * DH + e], kvacc[ph][dt2][r]);
        }
    }
    if (tid < 128) {
        int d = tid & 63;
        atomicAdd(&ksw[(bt * HEADS + hp * 2 + 0) * DH + d], ksp0);
        atomicAdd(&ksw[(bt * HEADS + hp * 2 + 1) * DH + d], ksp1);
    }
}

// ---------------------------------------------------------------------------
// K4: spatial pass B. grid (18, 4 head-pairs, BT), 256 threads (4 waves).
// GEMM xb@Wq (128 tok x 128 cols = 2 heads), q=fmap(.+bvec)*mw -> LDS,
// out = (q@kv) * z via MFMA.
// ---------------------------------------------------------------------------
__global__ __launch_bounds__(256) void k_spatial_out(
    const unsigned short* __restrict__ xb, const unsigned short* __restrict__ Wt,
    const float* __restrict__ bvec, const float* __restrict__ motion,
    const float* __restrict__ kvw, const float* __restrict__ ksw,
    float* __restrict__ out) {
    __shared__ __align__(16) char smem[51712];
    unsigned short* A_s = (unsigned short*)smem;            // 128 x 64 sh
    unsigned short* B_s = (unsigned short*)(smem + 16384);  // 128 x 64 sh
    char* qs  = smem;                                       // 128 tok x 256 B alias
    char* kvT = smem + 32768;                               // 128 rows x 128 B
    float* bvl = (float*)(smem + 49152);                    // 128
    float* mwv = (float*)(smem + 49664);                    // 128
    float* ksl = (float*)(smem + 50176);                    // 128 (2 heads x 64)
    float* zv  = (float*)(smem + 50688);                    // 256 (2 heads x 128)

    const int tile = blockIdx.x, hp = blockIdx.y, bt = blockIdx.z;
    const int tid = threadIdx.x, lane = tid & 63, w = tid >> 6;
    const int lm = lane & 15, quad = lane >> 4;
    const int mr = w & 1, nc = w >> 1;
    const int li8 = lane >> 3, lp = lane & 7;
    const int n0 = tile * 128;

    if (tid < 128) {
        bvl[tid] = bvec[(size_t)bt * TC + hp * 128 + tid];
        mwv[tid] = 1.f + tanhf(motion[(size_t)bt * NTOK + n0 + tid]);
        ksl[tid] = ksw[(bt * HEADS + hp * 2 + (tid >> 6)) * DH + (tid & 63)];
    }
    {   // kvT[head*64+e][d] = bf16(kvw[head][d][e]), swizzled
        int rr = tid & 127, hh = tid >> 7;
        int head = rr >> 6, e = rr & 63;
        const float* kvp = kvw + (size_t)(bt * HEADS + hp * 2 + head) * DH * DH;
#pragma unroll 8
        for (int d = hh * 32; d < hh * 32 + 32; ++d) {
            int p = (d >> 3) ^ (rr & 7);
            ((unsigned short*)(kvT + rr * 128 + p * 16))[d & 7] = f2bf(kvp[d * DH + e]);
        }
    }
    f32x4 acc[4][4];
#pragma unroll
    for (int i = 0; i < 4; ++i)
#pragma unroll
        for (int j = 0; j < 4; ++j) acc[i][j] = (f32x4)0.f;

    for (int kc = 0; kc < 8; ++kc) {
        __syncthreads();
#pragma unroll
        for (int l = 0; l < 4; ++l) {
            int rowbase = w * 32 + l * 8;
            int row = rowbase + li8;
            int c = lp ^ (row & 7);
            gload16(xb + ((size_t)(bt * NTOK + n0 + row)) * C + kc * 64 + c * 8,
                    A_s + rowbase * 64);
        }
#pragma unroll
        for (int l = 0; l < 4; ++l) {
            int rowbase = w * 32 + l * 8;
            int r = rowbase + li8;
            int c = lp ^ (r & 7);
            gload16(Wt + (size_t)(hp * 128 + r) * C + kc * 64 + c * 8,
                    B_s + rowbase * 64);
        }
        __syncthreads();
#pragma unroll
        for (int ks = 0; ks < 2; ++ks) {
            bf16x8 af[4], bfr[4];
#pragma unroll
            for (int i = 0; i < 4; ++i) {
                int row = mr * 64 + i * 16 + lm;
                int p = (ks * 4 + quad) ^ (row & 7);
                af[i] = *(const bf16x8*)&A_s[row * 64 + p * 8];
            }
#pragma unroll
            for (int j = 0; j < 4; ++j) {
                int row = nc * 64 + j * 16 + lm;
                int p = (ks * 4 + quad) ^ (row & 7);
                bfr[j] = *(const bf16x8*)&B_s[row * 64 + p * 8];
            }
#pragma unroll
            for (int i = 0; i < 4; ++i)
#pragma unroll
                for (int j = 0; j < 4; ++j)
                    acc[i][j] = __builtin_amdgcn_mfma_f32_16x16x32_bf16(
                        af[i], bfr[j], acc[i][j], 0, 0, 0);
        }
    }
    __syncthreads();
    // q -> qs (bf16, swizzled [tok][col 0..127])
#pragma unroll
    for (int i = 0; i < 4; ++i) {
#pragma unroll
        for (int j = 0; j < 4; ++j) {
            int cl = nc * 64 + j * 16 + lm;
            float bv = bvl[cl];
            int cch = cl >> 3;
#pragma unroll
            for (int r = 0; r < 4; ++r) {
                int tok = mr * 64 + i * 16 + quad * 4 + r;
                float qv = fmap(acc[i][j][r] + bv) * mwv[tok];
                int p = (cch & 8) | ((cch & 7) ^ (tok & 7));
                ((unsigned short*)(qs + tok * 256 + p * 16))[cl & 7] = f2bf(qv);
            }
        }
    }
    __syncthreads();
    {   // z per (head, tok)
        int head = tid >> 7, tok = tid & 127;
        float zd = 0.f;
#pragma unroll
        for (int tc3 = 0; tc3 < 8; ++tc3) {
            int cch = head * 8 + tc3;
            int p = (cch & 8) | ((cch & 7) ^ (tok & 7));
            bf16x8 q8 = *(const bf16x8*)(qs + tok * 256 + p * 16);
#pragma unroll
            for (int q = 0; q < 8; ++q)
                zd += bf2f((unsigned short)q8[q]) * ksl[head * 64 + tc3 * 8 + q];
        }
        zv[head * 128 + tok] = 1.f / (zd + EPS);
    }
    __syncthreads();
    // out = q @ kv ; wave (mr, nc): rows mr*64.., head nc
    f32x4 oacc[4][4];
#pragma unroll
    for (int i = 0; i < 4; ++i)
#pragma unroll
        for (int j = 0; j < 4; ++j) oacc[i][j] = (f32x4)0.f;
#pragma unroll
    for (int ks3 = 0; ks3 < 2; ++ks3) {
        bf16x8 aq[4], bk[4];
#pragma unroll
        for (int i = 0; i < 4; ++i) {
            int tok = mr * 64 + i * 16 + lm;
            int cch = nc * 8 + ks3 * 4 + quad;
            int p = (cch & 8) | ((cch & 7) ^ (tok & 7));
            aq[i] = *(const bf16x8*)(qs + tok * 256 + p * 16);
        }
#pragma unroll
        for (int j = 0; j < 4; ++j) {
            int row = nc * 64 + j * 16 + lm;
            int tcc = ks3 * 4 + quad;
            int p = tcc ^ (row & 7);
            bk[j] = *(const bf16x8*)(kvT + row * 128 + p * 16);
        }
#pragma unroll
        for (int i = 0; i < 4; ++i)
#pragma unroll
            for (int j = 0; j < 4; ++j)
                oacc[i][j] = __builtin_amdgcn_mfma_f32_16x16x32_bf16(
                    aq[i], bk[j], oacc[i][j], 0, 0, 0);
    }
    const int h = hp * 2 + nc;
#pragma unroll
    for (int i = 0; i < 4; ++i)
#pragma unroll
        for (int r = 0; r < 4; ++r) {
            int tok = mr * 64 + i * 16 + quad * 4 + r;
            float z = zv[nc * 128 + tok];
#pragma unroll
            for (int j = 0; j < 4; ++j)
                out[((size_t)(bt * NTOK + n0 + tok)) * C + h * DH + j * 16 + lm] =
                    oacc[i][j][r] * z;
        }
}

// ---------------------------------------------------------------------------
extern "C" void kernel_launch(void* const* d_in, const int* in_sizes, int n_in,
                              void* d_out, int out_size, void* d_ws, size_t ws_size,
                              hipStream_t stream) {
    (void)in_sizes; (void)n_in; (void)out_size; (void)ws_size;
    const float* x      = (const float*)d_in[0];
    const float* motion = (const float*)d_in[1];
    const float* W      = (const float*)d_in[2];
    const float* temb   = (const float*)d_in[3];
    float* out = (float*)d_out;
    float* ws  = (float*)d_ws;

    // ws layout (float offsets)
    float* kvw   = ws;                     // 1048576
    float* ksw   = kvw + 1048576;          // 16384
    float* xtraw = ksw + 16384;            // 16384
    float* mmraw = xtraw + 16384;          // 32
    float* qkvt  = mmraw + 32;             // 49152
    float* bias  = qkvt + 49152;           // 16384
    float* bvec  = bias + 16384;           // 49152
    unsigned short* Wt = (unsigned short*)(bvec + 49152);  // 1536*512 bf16
    unsigned short* xb = (unsigned short*)(Wt + (size_t)TC * C);  // 73728*512 bf16

    hipMemsetAsync(d_ws, 0,
                   (size_t)(1048576 + 16384 + 16384 + 32) * sizeof(float), stream);
    k_prep_w<<<dim3(48, 16), 256, 0, stream>>>(W, Wt);
    k_time_reduce<<<dim3(BT, 8), 256, 0, stream>>>(x, motion, xtraw, mmraw, xb);
    k_time_qkv<<<dim3(BT, 6), 256, 0, stream>>>(xtraw, temb, W, qkvt);
    k_time_attn<<<dim3(2, HEADS), 256, 0, stream>>>(qkvt, mmraw, temb, bias);
    k_bias_vec<<<dim3(BT, 6), 256, 0, stream>>>(bias, W, bvec);
    k_spatial_kv<<<dim3(6, 4, BT), 512, 0, stream>>>(xb, Wt, bvec, kvw, ksw);
    k_spatial_out<<<dim3(18, 4, BT), 256, 0, stream>>>(xb, Wt, bvec, motion,
                                                       kvw, ksw, out);
}

// Round 3
// 531.940 us; speedup vs baseline: 1.0777x; 1.0142x over previous
//
#include <hip/hip_runtime.h>
#include <cstddef>
#include <cstdint>

#define HEADS 8
#define DH 64
#define C 512
#define TC 1536
#define BT 32
#define NTOK 2304
#define TT 16
#define EPS 1e-6f

typedef __attribute__((ext_vector_type(8))) short bf16x8;
typedef __attribute__((ext_vector_type(4))) float f32x4;
typedef __attribute__((address_space(3))) void as3_void;
typedef __attribute__((address_space(1))) const void as1_cvoid;

#define SBAR() __builtin_amdgcn_s_barrier()
#define SCHED0() __builtin_amdgcn_sched_barrier(0)

__device__ __forceinline__ float fmap(float x) {
    return x > 0.f ? x + 1.f : __expf(x);
}
__device__ __forceinline__ unsigned short f2bf(float f) {
    unsigned int u = __float_as_uint(f);
    return (unsigned short)((u + 0x7fffu + ((u >> 16) & 1u)) >> 16);
}
__device__ __forceinline__ unsigned int pack2bf(float a, float b) {
    return (unsigned int)f2bf(a) | ((unsigned int)f2bf(b) << 16);
}
__device__ __forceinline__ float bf2f(unsigned short h) {
    return __uint_as_float(((unsigned int)h) << 16);
}
// async global->LDS DMA, 16B/lane. LDS dest = wave-uniform base + lane*16.
__device__ __forceinline__ void gload16(const void* g, void* l) {
    __builtin_amdgcn_global_load_lds((as1_cvoid*)(uintptr_t)g,
                                     (as3_void*)(uintptr_t)l, 16, 0, 0);
}

// ---------------------------------------------------------------------------
// K0: Wt[col][c] (bf16) = W[c][col]. grid (48,16).
// ---------------------------------------------------------------------------
__global__ __launch_bounds__(256) void k_prep_w(
    const float* __restrict__ W, unsigned short* __restrict__ Wt) {
    __shared__ float tile[32][33];
    int col0 = blockIdx.x * 32, c0 = blockIdx.y * 32;
    int tx = threadIdx.x & 31, ty = threadIdx.x >> 5;
#pragma unroll
    for (int j = 0; j < 4; ++j) {
        int c = ty + j * 8;
        tile[c][tx] = W[(size_t)(c0 + c) * TC + col0 + tx];
    }
    __syncthreads();
#pragma unroll
    for (int j = 0; j < 4; ++j) {
        int col = ty + j * 8;
        Wt[(size_t)(col0 + col) * C + c0 + tx] = f2bf(tile[tx][col]);
    }
}

// ---------------------------------------------------------------------------
// K1: x_time channel sums + motion mean sums + stage xb = bf16(x).
// grid (BT, 8), block 256; thread <-> 2 consecutive channels.
// ---------------------------------------------------------------------------
__global__ __launch_bounds__(256) void k_time_reduce(
    const float* __restrict__ x, const float* __restrict__ motion,
    float* __restrict__ xtraw, float* __restrict__ mmraw,
    unsigned short* __restrict__ xb) {
    int bt = blockIdx.x, sp = blockIdx.y, tid = threadIdx.x;
    int n0 = sp * 288, cid = tid * 2;
    const float* xp = x + ((size_t)(bt * NTOK + n0)) * C + cid;
    unsigned short* xbp = xb + ((size_t)(bt * NTOK + n0)) * C + cid;
    float s0 = 0.f, s1 = 0.f;
    for (int n = 0; n < 288; ++n) {
        float2 v = *(const float2*)(xp + (size_t)n * C);
        s0 += v.x;
        s1 += v.y;
        *(unsigned int*)(xbp + (size_t)n * C) = pack2bf(v.x, v.y);
    }
    atomicAdd(&xtraw[bt * C + cid], s0);
    atomicAdd(&xtraw[bt * C + cid + 1], s1);

    const float* mp = motion + (size_t)bt * NTOK + n0;
    float m = mp[tid];
    if (tid < 32) m += mp[256 + tid];
    __shared__ float red[256];
    red[tid] = m;
    __syncthreads();
    for (int s = 128; s > 0; s >>= 1) {
        if (tid < s) red[tid] += red[tid + s];
        __syncthreads();
    }
    if (tid == 0) atomicAdd(&mmraw[bt], red[0]);
}

// ---------------------------------------------------------------------------
// K2a: qkv_time[bt][col] = x_time[bt] @ W.  grid (BT, 6).
// ---------------------------------------------------------------------------
__global__ __launch_bounds__(256) void k_time_qkv(
    const float* __restrict__ xtraw, const float* __restrict__ temb,
    const float* __restrict__ W, float* __restrict__ qkvt) {
    int bt = blockIdx.x, col = blockIdx.y * 256 + threadIdx.x, tid = threadIdx.x;
    __shared__ float xl[C];
    xl[tid]       = xtraw[bt * C + tid]       * (1.f / NTOK) + temb[tid];
    xl[tid + 256] = xtraw[bt * C + tid + 256] * (1.f / NTOK) + temb[tid + 256];
    __syncthreads();
    float a = 0.f;
#pragma unroll 8
    for (int c = 0; c < C; ++c) a += xl[c] * W[(size_t)c * TC + col];
    qkvt[(size_t)bt * TC + col] = a;
}

// ---------------------------------------------------------------------------
// K2b: temporal linear attention -> bias[bt][c] = temb[c] + t_out.
// ---------------------------------------------------------------------------
__global__ __launch_bounds__(256) void k_time_attn(
    const float* __restrict__ qkvt, const float* __restrict__ mmraw,
    const float* __restrict__ temb, float* __restrict__ bias) {
    int b = blockIdx.x, h = blockIdx.y, tid = threadIdx.x;
    int d = tid & 63, g = tid >> 6;
    __shared__ float qs[TT][DH], ks[TT][DH], vs[TT][DH], ksum[DH];
    __shared__ float kvl[DH][DH];
    for (int t = g; t < TT; t += 4) {
        size_t base = (size_t)(b * TT + t) * TC + h * DH + d;
        float mwt = 1.f + tanhf(mmraw[b * TT + t] * (1.f / NTOK));
        qs[t][d] = fmap(qkvt[base]) * mwt;
        ks[t][d] = fmap(qkvt[base + C]);
        vs[t][d] = qkvt[base + 2 * C];
    }
    __syncthreads();
    if (g == 0) {
        float s = 0.f;
        for (int t = 0; t < TT; ++t) s += ks[t][d];
        ksum[d] = s;
    }
    float kva[16];
#pragma unroll
    for (int i = 0; i < 16; ++i) kva[i] = 0.f;
    for (int t = 0; t < TT; ++t) {
        float kd = ks[t][d];
#pragma unroll
        for (int i = 0; i < 16; ++i) kva[i] += kd * vs[t][g * 16 + i];
    }
#pragma unroll
    for (int i = 0; i < 16; ++i) kvl[d][g * 16 + i] = kva[i];
    __syncthreads();
    for (int tt = 0; tt < 4; ++tt) {
        int t = g * 4 + tt;
        float acc = 0.f, zden = 0.f;
        for (int dd = 0; dd < DH; ++dd) {
            float qv = qs[t][dd];
            acc  += qv * kvl[dd][d];
            zden += qv * ksum[dd];
        }
        bias[(size_t)(b * TT + t) * C + h * DH + d] =
            acc / (zden + EPS) + temb[h * DH + d];
    }
}

// ---------------------------------------------------------------------------
// K2c: bvec[bt][col] = bias[bt] @ W.  grid (BT, 6).
// ---------------------------------------------------------------------------
__global__ __launch_bounds__(256) void k_bias_vec(
    const float* __restrict__ bias, const float* __restrict__ W,
    float* __restrict__ bvec) {
    int bt = blockIdx.x, col = blockIdx.y * 256 + threadIdx.x, tid = threadIdx.x;
    __shared__ float bl[C];
    bl[tid]       = bias[bt * C + tid];
    bl[tid + 256] = bias[bt * C + tid + 256];
    __syncthreads();
    float a = 0.f;
#pragma unroll 8
    for (int c = 0; c < C; ++c) a += bl[c] * W[(size_t)c * TC + col];
    bvec[(size_t)bt * TC + col] = a;
}

// ---------------------------------------------------------------------------
// K3: spatial pass A. grid (6, 4 head-pairs, BT), 512 threads (8 waves).
// Per tile (128 tok): GEMM xb@W -> k|v for 2 heads (256 cols), BK=64.
// Deep pipeline (T3+T4): A triple-buffered (depth-2 prefetch, HBM-latency
// stream), B double-buffered (depth-1, L2-resident Wt). Counted s_waitcnt
// vmcnt(N) + raw s_barrier so prefetches stay in flight across barriers.
// Per-wave VMEM queue before the wait at step kc (order enforced by
// sched_barrier separators):
//   [A(kc):2][B(kc):4][A(kc+1):2][B(kc+1):4][A(kc+2):2] -> vmcnt(8)
//   kc==6: [A6:2][B6:4][A7:2][B7:4]                     -> vmcnt(6)
//   kc==7: [A7:2][B7:4]                                 -> vmcnt(0)
// Targets are always the queue's oldest entries, so any extra compiler VMEM
// ops can only over-drain (safe). Epilogue unchanged; kvT aliases B0
// (kc=7 computes from A1/B1, B0 dead). s_setprio(1) wraps the MFMA cluster.
// ---------------------------------------------------------------------------
__global__ __launch_bounds__(512) void k_spatial_kv(
    const unsigned short* __restrict__ xb, const unsigned short* __restrict__ Wt,
    const float* __restrict__ bvec, float* __restrict__ kvw,
    float* __restrict__ ksw) {
    __shared__ __align__(16) char smem[115712];
    unsigned short* const Abuf[3] = {
        (unsigned short*)smem,                  // A0: 128 x 64 sh
        (unsigned short*)(smem + 16384),        // A1
        (unsigned short*)(smem + 32768)};       // A2
    unsigned short* const Bbuf[2] = {
        (unsigned short*)(smem + 49152),        // B0: 256 x 64 sh
        (unsigned short*)(smem + 81920)};       // B1
    char* kvT = smem + 49152;                   // alias B0
    float* bvl = (float*)(smem + 114688);       // 256

    const int s = blockIdx.x, hp = blockIdx.y, bt = blockIdx.z;
    const int tid = threadIdx.x, lane = tid & 63, w = tid >> 6;
    const int lm = lane & 15, quad = lane >> 4;
    const int mr = w & 1, nc = w >> 1;
    const int li8 = lane >> 3, lp = lane & 7;

    if (tid < 256) {
        int h2 = tid >> 7, j2 = tid & 127;
        int wr = (j2 < 64) ? (C + (hp * 2 + h2) * DH + j2)
                           : (2 * C + (hp * 2 + h2) * DH + (j2 - 64));
        bvl[tid] = bvec[(size_t)bt * TC + wr];
    }
    // per-lane global source bases (constant over t, kc)
    const unsigned short* srcA[2];
#pragma unroll
    for (int l = 0; l < 2; ++l) {
        int row = w * 16 + l * 8 + li8;
        int c = lp ^ (row & 7);
        srcA[l] = xb + ((size_t)(bt * NTOK + row)) * C + c * 8;
    }
    const unsigned short* srcB[4];
#pragma unroll
    for (int l = 0; l < 4; ++l) {
        int r = w * 32 + l * 8 + li8;
        int c = lp ^ (r & 7);
        int h2 = r >> 7, j2 = r & 127;
        int wr = (j2 < 64) ? (C + (hp * 2 + h2) * DH + j2)
                           : (2 * C + (hp * 2 + h2) * DH + (j2 - 64));
        srcB[l] = Wt + (size_t)wr * C + c * 8;
    }

    float ksp0 = 0.f, ksp1 = 0.f;
    f32x4 kvacc[2][2];
#pragma unroll
    for (int a = 0; a < 2; ++a)
#pragma unroll
        for (int b = 0; b < 2; ++b) kvacc[a][b] = (f32x4)0.f;

    auto STAGE_A = [&](unsigned short* As, int n0, int kc) {
#pragma unroll
        for (int l = 0; l < 2; ++l)
            gload16(srcA[l] + (size_t)n0 * C + kc * 64, As + (w * 16 + l * 8) * 64);
    };
    auto STAGE_B = [&](unsigned short* Bs, int kc) {
#pragma unroll
        for (int l = 0; l < 4; ++l)
            gload16(srcB[l] + kc * 64, Bs + (w * 32 + l * 8) * 64);
    };

#pragma unroll 1
    for (int t = 0; t < 3; ++t) {
        const int n0 = (s * 3 + t) * 128;
        f32x4 acc[4][4];
#pragma unroll
        for (int i = 0; i < 4; ++i)
#pragma unroll
            for (int j = 0; j < 4; ++j) acc[i][j] = (f32x4)0.f;

        // prologue queue: [A0:2][B0:4][A1:2]
        STAGE_A(Abuf[0], n0, 0);
        STAGE_B(Bbuf[0], 0);
        SCHED0();
        STAGE_A(Abuf[1], n0, 1);
        SCHED0();
#pragma unroll
        for (int kc = 0; kc < 8; ++kc) {
            const unsigned short* As = Abuf[kc % 3];
            const unsigned short* Bs = Bbuf[kc & 1];
            if (kc < 7) {
                STAGE_B(Bbuf[(kc + 1) & 1], kc + 1);
                SCHED0();
            }
            if (kc < 6) {
                STAGE_A(Abuf[(kc + 2) % 3], n0, kc + 2);
                SCHED0();
            }
            if (kc < 6)
                asm volatile("s_waitcnt vmcnt(8)" ::: "memory");
            else if (kc == 6)
                asm volatile("s_waitcnt vmcnt(6)" ::: "memory");
            else
                asm volatile("s_waitcnt vmcnt(0)" ::: "memory");
            SBAR();
            SCHED0();
            __builtin_amdgcn_s_setprio(1);
#pragma unroll
            for (int ks = 0; ks < 2; ++ks) {
                bf16x8 af[4], bfr[4];
#pragma unroll
                for (int i = 0; i < 4; ++i) {
                    int row = mr * 64 + i * 16 + lm;
                    int p = (ks * 4 + quad) ^ (row & 7);
                    af[i] = *(const bf16x8*)&As[row * 64 + p * 8];
                }
#pragma unroll
                for (int j = 0; j < 4; ++j) {
                    int row = nc * 64 + j * 16 + lm;
                    int p = (ks * 4 + quad) ^ (row & 7);
                    bfr[j] = *(const bf16x8*)&Bs[row * 64 + p * 8];
                }
#pragma unroll
                for (int i = 0; i < 4; ++i)
#pragma unroll
                    for (int j = 0; j < 4; ++j)
                        acc[i][j] = __builtin_amdgcn_mfma_f32_16x16x32_bf16(
                            af[i], bfr[j], acc[i][j], 0, 0, 0);
            }
            __builtin_amdgcn_s_setprio(0);
            SCHED0();
            SBAR();
            SCHED0();
        }
        // ---- epilogue: per head of the pair (kvT aliases B0; kc=7 used A1/B1) ----
#pragma unroll 1
        for (int ph = 0; ph < 2; ++ph) {
            __syncthreads();
            if ((nc >> 1) == ph) {  // waves holding this head's 128 cols write kvT
#pragma unroll
                for (int i = 0; i < 4; ++i) {
                    int tokb = mr * 64 + i * 16 + quad * 4;
                    int tc = tokb >> 3;
#pragma unroll
                    for (int j = 0; j < 4; ++j) {
                        int cg = nc * 64 + j * 16 + lm;
                        int cl = cg & 127;
                        float bv = bvl[cg];
                        f32x4 a4 = acc[i][j];
                        float v0 = a4[0] + bv, v1 = a4[1] + bv;
                        float v2 = a4[2] + bv, v3 = a4[3] + bv;
                        if (cl < 64) {
                            v0 = fmap(v0); v1 = fmap(v1);
                            v2 = fmap(v2); v3 = fmap(v3);
                        }
                        int p = (tc & 8) | ((tc & 7) ^ (cl & 7));
                        uint2 pk;
                        pk.x = pack2bf(v0, v1);
                        pk.y = pack2bf(v2, v3);
                        *(uint2*)(kvT + cl * 256 + p * 16 + (tokb & 7) * 2) = pk;
                    }
                }
            }
            __syncthreads();
            if (tid < 128) {  // ksum partials: (d, token-half)
                int d = tid & 63, half = tid >> 6;
                float ssum = 0.f;
#pragma unroll
                for (int tc2 = 0; tc2 < 8; ++tc2) {
                    int tcc = half * 8 + tc2;
                    int p = (tcc & 8) | ((tcc & 7) ^ (d & 7));
                    bf16x8 v8 = *(const bf16x8*)(kvT + d * 256 + p * 16);
#pragma unroll
                    for (int q = 0; q < 8; ++q)
                        ssum += bf2f((unsigned short)v8[q]);
                }
                if (ph == 0) ksp0 += ssum; else ksp1 += ssum;
            }
            // kv += kT @ v (K = 128 tokens); wave -> (dt pair, et)
#pragma unroll
            for (int dt2 = 0; dt2 < 2; ++dt2) {
                int drow = (mr * 2 + dt2) * 16 + lm;
                int erow = 64 + nc * 16 + lm;
#pragma unroll
                for (int ks2 = 0; ks2 < 4; ++ks2) {
                    int tcc = ks2 * 4 + quad;
                    int pA = (tcc & 8) | ((tcc & 7) ^ (drow & 7));
                    int pB = (tcc & 8) | ((tcc & 7) ^ (erow & 7));
                    bf16x8 ak = *(const bf16x8*)(kvT + drow * 256 + pA * 16);
                    bf16x8 bv8 = *(const bf16x8*)(kvT + erow * 256 + pB * 16);
                    kvacc[ph][dt2] = __builtin_amdgcn_mfma_f32_16x16x32_bf16(
                        ak, bv8, kvacc[ph][dt2], 0, 0, 0);
                }
            }
        }
        __syncthreads();  // kvT (=B0) reads done before next tile's prefetch
    }
#pragma unroll
    for (int ph = 0; ph < 2; ++ph) {
        float* kvp = kvw + (size_t)(bt * HEADS + hp * 2 + ph) * DH * DH;
#pragma unroll
        for (int dt2 = 0; dt2 < 2; ++dt2) {
            int d0 = (mr * 2 + dt2) * 16 + quad * 4;
            int e = nc * 16 + lm;
#pragma unroll
            for (int r = 0; r < 4; ++r)
                atomicAdd(&kvp[(d0 + r) * DH + e], kvacc[ph][dt2][r]);
        }
    }
    if (tid < 128) {
        int d = tid & 63;
        atomicAdd(&ksw[(bt * HEADS + hp * 2 + 0) * DH + d], ksp0);
        atomicAdd(&ksw[(bt * HEADS + hp * 2 + 1) * DH + d], ksp1);
    }
}

// ---------------------------------------------------------------------------
// K4: spatial pass B. grid (18, 4 head-pairs, BT), 256 threads (4 waves).
// GEMM xb@Wq (128 tok x 128 cols = 2 heads), q=fmap(.+bvec)*mw -> LDS,
// out = (q@kv) * z via MFMA.
// ---------------------------------------------------------------------------
__global__ __launch_bounds__(256) void k_spatial_out(
    const unsigned short* __restrict__ xb, const unsigned short* __restrict__ Wt,
    const float* __restrict__ bvec, const float* __restrict__ motion,
    const float* __restrict__ kvw, const float* __restrict__ ksw,
    float* __restrict__ out) {
    __shared__ __align__(16) char smem[51712];
    unsigned short* A_s = (unsigned short*)smem;            // 128 x 64 sh
    unsigned short* B_s = (unsigned short*)(smem + 16384);  // 128 x 64 sh
    char* qs  = smem;                                       // 128 tok x 256 B alias
    char* kvT = smem + 32768;                               // 128 rows x 128 B
    float* bvl = (float*)(smem + 49152);                    // 128
    float* mwv = (float*)(smem + 49664);                    // 128
    float* ksl = (float*)(smem + 50176);                    // 128 (2 heads x 64)
    float* zv  = (float*)(smem + 50688);                    // 256 (2 heads x 128)

    const int tile = blockIdx.x, hp = blockIdx.y, bt = blockIdx.z;
    const int tid = threadIdx.x, lane = tid & 63, w = tid >> 6;
    const int lm = lane & 15, quad = lane >> 4;
    const int mr = w & 1, nc = w >> 1;
    const int li8 = lane >> 3, lp = lane & 7;
    const int n0 = tile * 128;

    if (tid < 128) {
        bvl[tid] = bvec[(size_t)bt * TC + hp * 128 + tid];
        mwv[tid] = 1.f + tanhf(motion[(size_t)bt * NTOK + n0 + tid]);
        ksl[tid] = ksw[(bt * HEADS + hp * 2 + (tid >> 6)) * DH + (tid & 63)];
    }
    {   // kvT[head*64+e][d] = bf16(kvw[head][d][e]), swizzled
        int rr = tid & 127, hh = tid >> 7;
        int head = rr >> 6, e = rr & 63;
        const float* kvp = kvw + (size_t)(bt * HEADS + hp * 2 + head) * DH * DH;
#pragma unroll 8
        for (int d = hh * 32; d < hh * 32 + 32; ++d) {
            int p = (d >> 3) ^ (rr & 7);
            ((unsigned short*)(kvT + rr * 128 + p * 16))[d & 7] = f2bf(kvp[d * DH + e]);
        }
    }
    f32x4 acc[4][4];
#pragma unroll
    for (int i = 0; i < 4; ++i)
#pragma unroll
        for (int j = 0; j < 4; ++j) acc[i][j] = (f32x4)0.f;

    for (int kc = 0; kc < 8; ++kc) {
        __syncthreads();
#pragma unroll
        for (int l = 0; l < 4; ++l) {
            int rowbase = w * 32 + l * 8;
            int row = rowbase + li8;
            int c = lp ^ (row & 7);
            gload16(xb + ((size_t)(bt * NTOK + n0 + row)) * C + kc * 64 + c * 8,
                    A_s + rowbase * 64);
        }
#pragma unroll
        for (int l = 0; l < 4; ++l) {
            int rowbase = w * 32 + l * 8;
            int r = rowbase + li8;
            int c = lp ^ (r & 7);
            gload16(Wt + (size_t)(hp * 128 + r) * C + kc * 64 + c * 8,
                    B_s + rowbase * 64);
        }
        __syncthreads();
#pragma unroll
        for (int ks = 0; ks < 2; ++ks) {
            bf16x8 af[4], bfr[4];
#pragma unroll
            for (int i = 0; i < 4; ++i) {
                int row = mr * 64 + i * 16 + lm;
                int p = (ks * 4 + quad) ^ (row & 7);
                af[i] = *(const bf16x8*)&A_s[row * 64 + p * 8];
            }
#pragma unroll
            for (int j = 0; j < 4; ++j) {
                int row = nc * 64 + j * 16 + lm;
                int p = (ks * 4 + quad) ^ (row & 7);
                bfr[j] = *(const bf16x8*)&B_s[row * 64 + p * 8];
            }
#pragma unroll
            for (int i = 0; i < 4; ++i)
#pragma unroll
                for (int j = 0; j < 4; ++j)
                    acc[i][j] = __builtin_amdgcn_mfma_f32_16x16x32_bf16(
                        af[i], bfr[j], acc[i][j], 0, 0, 0);
        }
    }
    __syncthreads();
    // q -> qs (bf16, swizzled [tok][col 0..127])
#pragma unroll
    for (int i = 0; i < 4; ++i) {
#pragma unroll
        for (int j = 0; j < 4; ++j) {
            int cl = nc * 64 + j * 16 + lm;
            float bv = bvl[cl];
            int cch = cl >> 3;
#pragma unroll
            for (int r = 0; r < 4; ++r) {
                int tok = mr * 64 + i * 16 + quad * 4 + r;
                float qv = fmap(acc[i][j][r] + bv) * mwv[tok];
                int p = (cch & 8) | ((cch & 7) ^ (tok & 7));
                ((unsigned short*)(qs + tok * 256 + p * 16))[cl & 7] = f2bf(qv);
            }
        }
    }
    __syncthreads();
    {   // z per (head, tok)
        int head = tid >> 7, tok = tid & 127;
        float zd = 0.f;
#pragma unroll
        for (int tc3 = 0; tc3 < 8; ++tc3) {
            int cch = head * 8 + tc3;
            int p = (cch & 8) | ((cch & 7) ^ (tok & 7));
            bf16x8 q8 = *(const bf16x8*)(qs + tok * 256 + p * 16);
#pragma unroll
            for (int q = 0; q < 8; ++q)
                zd += bf2f((unsigned short)q8[q]) * ksl[head * 64 + tc3 * 8 + q];
        }
        zv[head * 128 + tok] = 1.f / (zd + EPS);
    }
    __syncthreads();
    // out = q @ kv ; wave (mr, nc): rows mr*64.., head nc
    f32x4 oacc[4][4];
#pragma unroll
    for (int i = 0; i < 4; ++i)
#pragma unroll
        for (int j = 0; j < 4; ++j) oacc[i][j] = (f32x4)0.f;
#pragma unroll
    for (int ks3 = 0; ks3 < 2; ++ks3) {
        bf16x8 aq[4], bk[4];
#pragma unroll
        for (int i = 0; i < 4; ++i) {
            int tok = mr * 64 + i * 16 + lm;
            int cch = nc * 8 + ks3 * 4 + quad;
            int p = (cch & 8) | ((cch & 7) ^ (tok & 7));
            aq[i] = *(const bf16x8*)(qs + tok * 256 + p * 16);
        }
#pragma unroll
        for (int j = 0; j < 4; ++j) {
            int row = nc * 64 + j * 16 + lm;
            int tcc = ks3 * 4 + quad;
            int p = tcc ^ (row & 7);
            bk[j] = *(const bf16x8*)(kvT + row * 128 + p * 16);
        }
#pragma unroll
        for (int i = 0; i < 4; ++i)
#pragma unroll
            for (int j = 0; j < 4; ++j)
                oacc[i][j] = __builtin_amdgcn_mfma_f32_16x16x32_bf16(
                    aq[i], bk[j], oacc[i][j], 0, 0, 0);
    }
    const int h = hp * 2 + nc;
#pragma unroll
    for (int i = 0; i < 4; ++i)
#pragma unroll
        for (int r = 0; r < 4; ++r) {
            int tok = mr * 64 + i * 16 + quad * 4 + r;
            float z = zv[nc * 128 + tok];
#pragma unroll
            for (int j = 0; j < 4; ++j)
                out[((size_t)(bt * NTOK + n0 + tok)) * C + h * DH + j * 16 + lm] =
                    oacc[i][j][r] * z;
        }
}

// ---------------------------------------------------------------------------
extern "C" void kernel_launch(void* const* d_in, const int* in_sizes, int n_in,
                              void* d_out, int out_size, void* d_ws, size_t ws_size,
                              hipStream_t stream) {
    (void)in_sizes; (void)n_in; (void)out_size; (void)ws_size;
    const float* x      = (const float*)d_in[0];
    const float* motion = (const float*)d_in[1];
    const float* W      = (const float*)d_in[2];
    const float* temb   = (const float*)d_in[3];
    float* out = (float*)d_out;
    float* ws  = (float*)d_ws;

    // ws layout (float offsets)
    float* kvw   = ws;                     // 1048576
    float* ksw   = kvw + 1048576;          // 16384
    float* xtraw = ksw + 16384;            // 16384
    float* mmraw = xtraw + 16384;          // 32
    float* qkvt  = mmraw + 32;             // 49152
    float* bias  = qkvt + 49152;           // 16384
    float* bvec  = bias + 16384;           // 49152
    unsigned short* Wt = (unsigned short*)(bvec + 49152);  // 1536*512 bf16
    unsigned short* xb = (unsigned short*)(Wt + (size_t)TC * C);  // 73728*512 bf16

    hipMemsetAsync(d_ws, 0,
                   (size_t)(1048576 + 16384 + 16384 + 32) * sizeof(float), stream);
    k_prep_w<<<dim3(48, 16), 256, 0, stream>>>(W, Wt);
    k_time_reduce<<<dim3(BT, 8), 256, 0, stream>>>(x, motion, xtraw, mmraw, xb);
    k_time_qkv<<<dim3(BT, 6), 256, 0, stream>>>(xtraw, temb, W, qkvt);
    k_time_attn<<<dim3(2, HEADS), 256, 0, stream>>>(qkvt, mmraw, temb, bias);
    k_bias_vec<<<dim3(BT, 6), 256, 0, stream>>>(bias, W, bvec);
    k_spatial_kv<<<dim3(6, 4, BT), 512, 0, stream>>>(xb, Wt, bvec, kvw, ksw);
    k_spatial_out<<<dim3(18, 4, BT), 256, 0, stream>>>(xb, Wt, bvec, motion,
                                                       kvw, ksw, out);
}